// Round 2
// baseline (1263.697 us; speedup 1.0000x reference)
//
#include <hip/hip_runtime.h>
#include <stdint.h>

#define NB 2
#define NS 2048
#define ND 2048
#define NH 16
#define NHD 128
#define NFF 8192
#define NBS (NB*NS)   // 4096 rows

typedef unsigned short u16;
typedef __attribute__((ext_vector_type(8))) short bf16x8;   // 8 bf16 = 4 VGPRs
typedef __attribute__((ext_vector_type(4))) unsigned short u16x4;
typedef __attribute__((ext_vector_type(4))) float f32x4;

__device__ __forceinline__ u16 f2bf(float f) {
  union { float f; unsigned u; } v; v.f = f;
  unsigned r = v.u + 0x7fffu + ((v.u >> 16) & 1u);   // RNE
  return (u16)(r >> 16);
}
__device__ __forceinline__ float bf2f(u16 h) {
  union { unsigned u; float f; } v; v.u = ((unsigned)h) << 16;
  return v.f;
}
__device__ __forceinline__ void async_cp16(const void* g, void* l) {
  __builtin_amdgcn_global_load_lds((const __attribute__((address_space(1))) void*)g,
                                   (__attribute__((address_space(3))) void*)l, 16, 0, 0);
}

// ---------------- fp32 -> bf16 ----------------
__global__ void cvt_bf16_kernel(const float* __restrict__ in, u16* __restrict__ out, int n4) {
  int i = blockIdx.x * blockDim.x + threadIdx.x;
  if (i >= n4) return;
  float4 v = reinterpret_cast<const float4*>(in)[i];
  u16x4 o; o.x = f2bf(v.x); o.y = f2bf(v.y); o.z = f2bf(v.z); o.w = f2bf(v.w);
  reinterpret_cast<u16x4*>(out)[i] = o;
}

// ---------------- RMSNorm (fp32 in -> bf16 out), one block per row ----------------
__global__ __launch_bounds__(256) void rmsnorm_kernel(const float* __restrict__ x,
                                                      const float* __restrict__ w,
                                                      u16* __restrict__ out) {
  const int row = blockIdx.x, tid = threadIdx.x;
  const float* xr = x + (size_t)row * ND;
  float4 a = *reinterpret_cast<const float4*>(xr + tid * 8);
  float4 b = *reinterpret_cast<const float4*>(xr + tid * 8 + 4);
  float ss = a.x*a.x + a.y*a.y + a.z*a.z + a.w*a.w
           + b.x*b.x + b.y*b.y + b.z*b.z + b.w*b.w;
#pragma unroll
  for (int off = 32; off > 0; off >>= 1) ss += __shfl_down(ss, off);
  __shared__ float red[4];
  __shared__ float rinv_s;
  if ((tid & 63) == 0) red[tid >> 6] = ss;
  __syncthreads();
  if (tid == 0) rinv_s = rsqrtf((red[0] + red[1] + red[2] + red[3]) * (1.0f / ND) + 1e-6f);
  __syncthreads();
  const float rinv = rinv_s;
  const float* wr = w + tid * 8;
  u16* orow = out + (size_t)row * ND + tid * 8;
  float vs[8] = {a.x, a.y, a.z, a.w, b.x, b.y, b.z, b.w};
#pragma unroll
  for (int j = 0; j < 8; ++j) orow[j] = f2bf(vs[j] * rinv * wr[j]);
}

// ---------------- RoPE cos/sin table [S][64] ----------------
__global__ void rope_table_kernel(float* __restrict__ cosT, float* __restrict__ sinT) {
  int i = blockIdx.x * blockDim.x + threadIdx.x;
  if (i >= NS * 64) return;
  int s = i >> 6, d = i & 63;
  float freq = expf(-(float)d * (9.210340371976184f / 64.0f));  // 10000^(-d/64)
  float ang = (float)s * freq;
  cosT[i] = cosf(ang);
  sinT[i] = sinf(ang);
}

// ---------------- RoPE for Q: [B,S,H*HD] bf16 -> [B*H, S, HD] bf16, pre-scaled 1/sqrt(HD) ----
__global__ void rope_q_kernel(const u16* __restrict__ qraw, const float* __restrict__ cosT,
                              const float* __restrict__ sinT, u16* __restrict__ qout) {
  int i = blockIdx.x * blockDim.x + threadIdx.x;
  if (i >= NB * NS * NH * 64) return;
  int d = i & 63, h = (i >> 6) & 15, s = (i >> 10) & (NS - 1), b = i >> 21;
  size_t rrow = ((size_t)(b * NS + s)) * ND + h * NHD;
  float t1 = bf2f(qraw[rrow + d]);
  float t2 = bf2f(qraw[rrow + d + 64]);
  float c = cosT[(s << 6) + d], sn = sinT[(s << 6) + d];
  const float scale = 0.08838834764831845f;  // 1/sqrt(128)
  size_t orow = (((size_t)(b * NH + h)) * NS + s) * NHD;
  qout[orow + d]      = f2bf((t1 * c - t2 * sn) * scale);
  qout[orow + d + 64] = f2bf((t2 * c + t1 * sn) * scale);
}

// ---------------- RoPE for K + copy V: kv [B,S,256] bf16 -> k,v [B,S,HD] bf16 ----------------
__global__ void rope_kv_kernel(const u16* __restrict__ kvraw, const float* __restrict__ cosT,
                               const float* __restrict__ sinT, u16* __restrict__ kout,
                               u16* __restrict__ vout) {
  int i = blockIdx.x * blockDim.x + threadIdx.x;
  if (i >= NB * NS * 64) return;
  int d = i & 63, s = (i >> 6) & (NS - 1), b = i >> 17;
  size_t rrow = ((size_t)(b * NS + s)) * 256;
  float t1 = bf2f(kvraw[rrow + d]);
  float t2 = bf2f(kvraw[rrow + d + 64]);
  float c = cosT[(s << 6) + d], sn = sinT[(s << 6) + d];
  size_t orow = ((size_t)(b * NS + s)) * NHD;
  kout[orow + d]      = f2bf(t1 * c - t2 * sn);
  kout[orow + d + 64] = f2bf(t2 * c + t1 * sn);
  vout[orow + d]      = kvraw[rrow + 128 + d];
  vout[orow + d + 64] = kvraw[rrow + 128 + d + 64];
}

// ---------------- GEMM: C[M,N] = A[M,K](bf16) @ W[N,K]^T(bf16) ----------------
// 128x128 tile, BK=64, 4 waves (2x2), 4x4 acc of 16x16x32 MFMA per wave.
// EPI: 0 = store bf16; 1 = store fp32 acc + fp32 Aux; 2 = store bf16 silu(Aux_bf16)*acc
// NOTE: Out and Aux may alias (EPI 2 in-place) -> no __restrict__ on them.
template <int EPI>
__global__ __launch_bounds__(256) void gemm_kernel(const u16* __restrict__ A,
                                                   const u16* __restrict__ W,
                                                   void* Out,
                                                   const void* Aux,
                                                   int M, int N, int K) {
  __shared__ __align__(16) u16 Asm[128 * 64];
  __shared__ __align__(16) u16 Bsm[128 * 64];
  const int tid = threadIdx.x, wave = tid >> 6, lane = tid & 63;
  const int m0 = blockIdx.y * 128, n0 = blockIdx.x * 128;
  const int wr = wave >> 1, wc = wave & 1;

  f32x4 acc[4][4];
#pragma unroll
  for (int i = 0; i < 4; ++i)
#pragma unroll
    for (int j = 0; j < 4; ++j) acc[i][j] = (f32x4){0.f, 0.f, 0.f, 0.f};

  for (int k0 = 0; k0 < K; k0 += 64) {
#pragma unroll
    for (int p = 0; p < 4; ++p) {
      int linear = p * 4096 + tid * 16;        // byte offset within 16KB tile
      int r = linear >> 7;                     // 128B per row (64 bf16)
      int kk = (linear & 127) >> 1;
      int ldsoff = p * 4096 + wave * 1024;     // wave-uniform dest base
      async_cp16(A + (size_t)(m0 + r) * K + k0 + kk, (char*)Asm + ldsoff);
      async_cp16(W + (size_t)(n0 + r) * K + k0 + kk, (char*)Bsm + ldsoff);
    }
    __syncthreads();   // compiler drains vmcnt before s_barrier
#pragma unroll
    for (int kk = 0; kk < 64; kk += 32) {
      const int ko = kk + (lane >> 4) * 8;
      bf16x8 af[4], bfr[4];
#pragma unroll
      for (int mi = 0; mi < 4; ++mi)
        af[mi] = *(const bf16x8*)&Asm[(wr * 64 + mi * 16 + (lane & 15)) * 64 + ko];
#pragma unroll
      for (int ni = 0; ni < 4; ++ni)
        bfr[ni] = *(const bf16x8*)&Bsm[(wc * 64 + ni * 16 + (lane & 15)) * 64 + ko];
#pragma unroll
      for (int mi = 0; mi < 4; ++mi)
#pragma unroll
        for (int ni = 0; ni < 4; ++ni)
          acc[mi][ni] = __builtin_amdgcn_mfma_f32_16x16x32_bf16(af[mi], bfr[ni], acc[mi][ni], 0, 0, 0);
    }
    __syncthreads();
  }

  // epilogue: C/D layout col=lane&15, row=(lane>>4)*4+reg
#pragma unroll
  for (int mi = 0; mi < 4; ++mi) {
    const int row_b = m0 + wr * 64 + mi * 16 + (lane >> 4) * 4;
#pragma unroll
    for (int ni = 0; ni < 4; ++ni) {
      const int col = n0 + wc * 64 + ni * 16 + (lane & 15);
#pragma unroll
      for (int r = 0; r < 4; ++r) {
        size_t idx = (size_t)(row_b + r) * N + col;
        float v = acc[mi][ni][r];
        if constexpr (EPI == 0) {
          ((u16*)Out)[idx] = f2bf(v);
        } else if constexpr (EPI == 1) {
          ((float*)Out)[idx] = v + ((const float*)Aux)[idx];
        } else {
          float a1 = bf2f(((const u16*)Aux)[idx]);
          float s = a1 / (1.0f + expf(-a1));   // silu
          ((u16*)Out)[idx] = f2bf(s * v);
        }
      }
    }
  }
}

// ---------------- Flash attention with ALiBi + causal ----------------
// grid (S/64, B*H), 256 threads = 4 waves, wave handles 16 q rows, KV tiles of 32.
__global__ __launch_bounds__(256) void attn_kernel(const u16* __restrict__ q,
                                                   const u16* __restrict__ kg,
                                                   const u16* __restrict__ vg,
                                                   u16* __restrict__ out) {
  __shared__ __align__(16) u16 Plds[4][16 * 32];
  __shared__ __align__(16) u16 Vlds[32 * 128];
  const int tid = threadIdx.x, wave = tid >> 6, lane = tid & 63;
  const int q0 = blockIdx.x * 64;
  const int bh = blockIdx.y, b = bh >> 4, h = bh & 15;
  const float slope = exp2f(-0.5f * (float)(h + 1));
  const int crow = (lane >> 4) * 4;

  bf16x8 qf[4];
  {
    const int qrow = q0 + wave * 16 + (lane & 15);
    const u16* qbase = q + (((size_t)bh * NS) + qrow) * NHD + (lane >> 4) * 8;
#pragma unroll
    for (int kc = 0; kc < 4; ++kc) qf[kc] = *(const bf16x8*)(qbase + kc * 32);
  }

  float Mr[4], Lr[4];
  f32x4 O[8];
#pragma unroll
  for (int r = 0; r < 4; ++r) { Mr[r] = -__builtin_inff(); Lr[r] = 0.f; }
#pragma unroll
  for (int t = 0; t < 8; ++t) O[t] = (f32x4){0.f, 0.f, 0.f, 0.f};

  const int ntiles = (q0 + 64) >> 5;
  for (int t0 = 0; t0 < ntiles; ++t0) {
    const int kv0 = t0 * 32;
    f32x4 s0 = (f32x4){0.f, 0.f, 0.f, 0.f}, s1 = (f32x4){0.f, 0.f, 0.f, 0.f};
    const u16* kb = kg + (((size_t)b * NS) + kv0 + (lane & 15)) * NHD + (lane >> 4) * 8;
#pragma unroll
    for (int kc = 0; kc < 4; ++kc) {
      bf16x8 k0f = *(const bf16x8*)(kb + kc * 32);
      bf16x8 k1f = *(const bf16x8*)(kb + (size_t)16 * NHD + kc * 32);
      s0 = __builtin_amdgcn_mfma_f32_16x16x32_bf16(qf[kc], k0f, s0, 0, 0, 0);
      s1 = __builtin_amdgcn_mfma_f32_16x16x32_bf16(qf[kc], k1f, s1, 0, 0, 0);
    }
    float p0[4], p1[4], esc[4];
#pragma unroll
    for (int r = 0; r < 4; ++r) {
      const int sq = q0 + wave * 16 + crow + r;
      const int t0c = kv0 + (lane & 15), t1c = t0c + 16;
      float v0 = (t0c <= sq) ? s0[r] - slope * (float)(sq - t0c) : -1e9f;
      float v1 = (t1c <= sq) ? s1[r] - slope * (float)(sq - t1c) : -1e9f;
      float mx = fmaxf(v0, v1);
      mx = fmaxf(mx, __shfl_xor(mx, 1));
      mx = fmaxf(mx, __shfl_xor(mx, 2));
      mx = fmaxf(mx, __shfl_xor(mx, 4));
      mx = fmaxf(mx, __shfl_xor(mx, 8));
      float newM = fmaxf(Mr[r], mx);
      esc[r] = __expf(Mr[r] - newM);
      p0[r] = __expf(v0 - newM);
      p1[r] = __expf(v1 - newM);
      float rs = p0[r] + p1[r];
      rs += __shfl_xor(rs, 1);
      rs += __shfl_xor(rs, 2);
      rs += __shfl_xor(rs, 4);
      rs += __shfl_xor(rs, 8);
      Lr[r] = Lr[r] * esc[r] + rs;
      Mr[r] = newM;
    }
#pragma unroll
    for (int t = 0; t < 8; ++t) {
      O[t][0] *= esc[0]; O[t][1] *= esc[1]; O[t][2] *= esc[2]; O[t][3] *= esc[3];
    }
    __syncthreads();
#pragma unroll
    for (int r = 0; r < 4; ++r) {
      Plds[wave][(crow + r) * 32 + (lane & 15)]      = f2bf(p0[r]);
      Plds[wave][(crow + r) * 32 + 16 + (lane & 15)] = f2bf(p1[r]);
    }
    {
      const u16* vsrc = vg + ((size_t)b * NS + kv0) * NHD;
#pragma unroll
      for (int p = 0; p < 2; ++p) {
        int idx = (p * 256 + tid) * 8;
        *(bf16x8*)&Vlds[idx] = *(const bf16x8*)(vsrc + idx);
      }
    }
    __syncthreads();
    const bf16x8 pf = *(const bf16x8*)&Plds[wave][(lane & 15) * 32 + (lane >> 4) * 8];
    const short* Vs = (const short*)Vlds;
#pragma unroll
    for (int t = 0; t < 8; ++t) {
      bf16x8 vf;
#pragma unroll
      for (int i = 0; i < 8; ++i)
        vf[i] = Vs[((lane >> 4) * 8 + i) * NHD + t * 16 + (lane & 15)];
      O[t] = __builtin_amdgcn_mfma_f32_16x16x32_bf16(pf, vf, O[t], 0, 0, 0);
    }
  }
#pragma unroll
  for (int t = 0; t < 8; ++t) {
#pragma unroll
    for (int r = 0; r < 4; ++r) {
      const int sq = q0 + wave * 16 + crow + r;
      out[((size_t)b * NS + sq) * ND + h * NHD + t * 16 + (lane & 15)] = f2bf(O[t][r] / Lr[r]);
    }
  }
}

// ---------------- host ----------------
extern "C" void kernel_launch(void* const* d_in, const int* in_sizes, int n_in,
                              void* d_out, int out_size, void* d_ws, size_t ws_size,
                              hipStream_t stream) {
  const float* x   = (const float*)d_in[0];
  const float* wn1 = (const float*)d_in[2];
  const float* wn2 = (const float*)d_in[3];
  const float* qw  = (const float*)d_in[4];
  const float* kvw = (const float*)d_in[5];
  const float* ow  = (const float*)d_in[6];
  const float* w1  = (const float*)d_in[7];
  const float* w2  = (const float*)d_in[8];
  const float* w3  = (const float*)d_in[9];
  float* out = (float*)d_out;

  const size_t MiB = 1024 * 1024;
  // Lifetime-aliased layout, 161 MiB total:
  //  [0,32)    R_W   weight scratch (bf16), reused sequentially for all weights
  //  [32,48)   Hbf   rmsnorm output (h1, later h2)
  //  [48,49)   COS/SIN rope tables
  //  [49,65)   QRAW  (dead after rope_q)  -> reused as AO (attn out)
  //  [65,97)   QB(16)+KB(1)+VB(1)+KVRAW(2) (dead after attn) -> reused as X2 (fp32)
  //  [97,161)  A1    FFN activation (bf16 [4096][8192])
  const size_t NEED = 161 * MiB;
  if (ws_size < NEED) return;  // readable failure (zero output) instead of OOB fault

  char* ws = (char*)d_ws;
  u16*   R_W   = (u16*)(ws);
  u16*   Hbf   = (u16*)(ws + 32 * MiB);
  float* COS   = (float*)(ws + 48 * MiB);
  float* SIN   = (float*)(ws + 48 * MiB + 512 * 1024);
  u16*   QRAW  = (u16*)(ws + 49 * MiB);
  u16*   AO    = QRAW;                       // alias: QRAW dead after rope_q
  u16*   QB    = (u16*)(ws + 65 * MiB);
  u16*   KB    = (u16*)(ws + 81 * MiB);
  u16*   VB    = (u16*)(ws + 82 * MiB);
  u16*   KVRAW = (u16*)(ws + 83 * MiB);
  float* X2    = (float*)(ws + 65 * MiB);    // alias: QB/KB/VB/KVRAW dead after attn
  u16*   A1    = (u16*)(ws + 97 * MiB);

  auto cvt = [&](const float* src, u16* dst, size_t n) {
    int n4 = (int)(n / 4);
    cvt_bf16_kernel<<<(n4 + 255) / 256, 256, 0, stream>>>(src, dst, n4);
  };

  rope_table_kernel<<<(NS * 64 + 255) / 256, 256, 0, stream>>>(COS, SIN);

  // h = rmsnorm(x, wn1)
  rmsnorm_kernel<<<NBS, 256, 0, stream>>>(x, wn1, Hbf);

  // q_raw = h @ qw^T
  cvt(qw, R_W, (size_t)ND * ND);
  gemm_kernel<0><<<dim3(ND / 128, NBS / 128), 256, 0, stream>>>(Hbf, R_W, (void*)QRAW, nullptr, NBS, ND, ND);
  // kv_raw = h @ kvw^T
  cvt(kvw, R_W, (size_t)256 * ND);
  gemm_kernel<0><<<dim3(256 / 128, NBS / 128), 256, 0, stream>>>(Hbf, R_W, (void*)KVRAW, nullptr, NBS, 256, ND);

  // rope
  rope_q_kernel<<<(NB * NS * NH * 64) / 256, 256, 0, stream>>>(QRAW, COS, SIN, QB);
  rope_kv_kernel<<<(NB * NS * 64) / 256, 256, 0, stream>>>(KVRAW, COS, SIN, KB, VB);

  // attention -> AO (over dead QRAW)
  attn_kernel<<<dim3(NS / 64, NB * NH), 256, 0, stream>>>(QB, KB, VB, AO);

  // x2 = x + ao @ ow^T   (X2 over dead QB/KB/VB/KVRAW)
  cvt(ow, R_W, (size_t)ND * ND);
  gemm_kernel<1><<<dim3(ND / 128, NBS / 128), 256, 0, stream>>>(AO, R_W, (void*)X2, (const void*)x, NBS, ND, ND);

  // h2 = rmsnorm(x2, wn2)  (reuse Hbf)
  rmsnorm_kernel<<<NBS, 256, 0, stream>>>(X2, wn2, Hbf);

  // a1 = h2 @ w1^T (raw)
  cvt(w1, R_W, (size_t)NFF * ND);
  gemm_kernel<0><<<dim3(NFF / 128, NBS / 128), 256, 0, stream>>>(Hbf, R_W, (void*)A1, nullptr, NBS, NFF, ND);
  // g = silu(a1) * (h2 @ w2^T)  (in-place over A1)
  cvt(w2, R_W, (size_t)NFF * ND);
  gemm_kernel<2><<<dim3(NFF / 128, NBS / 128), 256, 0, stream>>>(Hbf, R_W, (void*)A1, (const void*)A1, NBS, NFF, ND);

  // out = x2 + g @ w3^T
  cvt(w3, R_W, (size_t)ND * NFF);
  gemm_kernel<1><<<dim3(ND / 128, NBS / 128), 256, 0, stream>>>(A1, R_W, (void*)out, (const void*)X2, NBS, ND, NFF);
}

// Round 3
// 1099.735 us; speedup vs baseline: 1.1491x; 1.1491x over previous
//
#include <hip/hip_runtime.h>
#include <stdint.h>

#define NB 2
#define NS 2048
#define ND 2048
#define NH 16
#define NHD 128
#define NFF 8192
#define NBS (NB*NS)   // 4096 rows

typedef unsigned short u16;
typedef __attribute__((ext_vector_type(8))) short bf16x8;   // 8 bf16 = 4 VGPRs
typedef __attribute__((ext_vector_type(4))) unsigned short u16x4;
typedef __attribute__((ext_vector_type(4))) float f32x4;

__device__ __forceinline__ u16 f2bf(float f) {
  union { float f; unsigned u; } v; v.f = f;
  unsigned r = v.u + 0x7fffu + ((v.u >> 16) & 1u);   // RNE
  return (u16)(r >> 16);
}
__device__ __forceinline__ float bf2f(u16 h) {
  union { unsigned u; float f; } v; v.u = ((unsigned)h) << 16;
  return v.f;
}
__device__ __forceinline__ void async_cp16(const void* g, void* l) {
  __builtin_amdgcn_global_load_lds((const __attribute__((address_space(1))) void*)g,
                                   (__attribute__((address_space(3))) void*)l, 16, 0, 0);
}

// ---------------- fp32 -> bf16 ----------------
__global__ void cvt_bf16_kernel(const float* __restrict__ in, u16* __restrict__ out, int n4) {
  int i = blockIdx.x * blockDim.x + threadIdx.x;
  if (i >= n4) return;
  float4 v = reinterpret_cast<const float4*>(in)[i];
  u16x4 o; o.x = f2bf(v.x); o.y = f2bf(v.y); o.z = f2bf(v.z); o.w = f2bf(v.w);
  reinterpret_cast<u16x4*>(out)[i] = o;
}

// ---------------- RMSNorm (fp32 in -> bf16 out), one block per row ----------------
__global__ __launch_bounds__(256) void rmsnorm_kernel(const float* __restrict__ x,
                                                      const float* __restrict__ w,
                                                      u16* __restrict__ out) {
  const int row = blockIdx.x, tid = threadIdx.x;
  const float* xr = x + (size_t)row * ND;
  float4 a = *reinterpret_cast<const float4*>(xr + tid * 8);
  float4 b = *reinterpret_cast<const float4*>(xr + tid * 8 + 4);
  float ss = a.x*a.x + a.y*a.y + a.z*a.z + a.w*a.w
           + b.x*b.x + b.y*b.y + b.z*b.z + b.w*b.w;
#pragma unroll
  for (int off = 32; off > 0; off >>= 1) ss += __shfl_down(ss, off);
  __shared__ float red[4];
  __shared__ float rinv_s;
  if ((tid & 63) == 0) red[tid >> 6] = ss;
  __syncthreads();
  if (tid == 0) rinv_s = rsqrtf((red[0] + red[1] + red[2] + red[3]) * (1.0f / ND) + 1e-6f);
  __syncthreads();
  const float rinv = rinv_s;
  const float* wr = w + tid * 8;
  u16* orow = out + (size_t)row * ND + tid * 8;
  float vs[8] = {a.x, a.y, a.z, a.w, b.x, b.y, b.z, b.w};
#pragma unroll
  for (int j = 0; j < 8; ++j) orow[j] = f2bf(vs[j] * rinv * wr[j]);
}

// ---------------- RoPE cos/sin table [S][64] ----------------
__global__ void rope_table_kernel(float* __restrict__ cosT, float* __restrict__ sinT) {
  int i = blockIdx.x * blockDim.x + threadIdx.x;
  if (i >= NS * 64) return;
  int s = i >> 6, d = i & 63;
  float freq = expf(-(float)d * (9.210340371976184f / 64.0f));  // 10000^(-d/64)
  float ang = (float)s * freq;
  cosT[i] = cosf(ang);
  sinT[i] = sinf(ang);
}

// ---------------- RoPE for Q: [B,S,H*HD] bf16 -> [B*H, S, HD] bf16, pre-scaled 1/sqrt(HD) ----
__global__ void rope_q_kernel(const u16* __restrict__ qraw, const float* __restrict__ cosT,
                              const float* __restrict__ sinT, u16* __restrict__ qout) {
  int i = blockIdx.x * blockDim.x + threadIdx.x;
  if (i >= NB * NS * NH * 64) return;
  int d = i & 63, h = (i >> 6) & 15, s = (i >> 10) & (NS - 1), b = i >> 21;
  size_t rrow = ((size_t)(b * NS + s)) * ND + h * NHD;
  float t1 = bf2f(qraw[rrow + d]);
  float t2 = bf2f(qraw[rrow + d + 64]);
  float c = cosT[(s << 6) + d], sn = sinT[(s << 6) + d];
  const float scale = 0.08838834764831845f;  // 1/sqrt(128)
  size_t orow = (((size_t)(b * NH + h)) * NS + s) * NHD;
  qout[orow + d]      = f2bf((t1 * c - t2 * sn) * scale);
  qout[orow + d + 64] = f2bf((t2 * c + t1 * sn) * scale);
}

// ---- RoPE for K + transpose-copy V: kv [B,S,256] bf16 -> k [B,S,HD], vt [B,128,S] ----
__global__ void rope_kv_kernel(const u16* __restrict__ kvraw, const float* __restrict__ cosT,
                               const float* __restrict__ sinT, u16* __restrict__ kout,
                               u16* __restrict__ vtout) {
  int i = blockIdx.x * blockDim.x + threadIdx.x;
  if (i >= NB * NS * 64) return;
  int d = i & 63, s = (i >> 6) & (NS - 1), b = i >> 17;
  size_t rrow = ((size_t)(b * NS + s)) * 256;
  float t1 = bf2f(kvraw[rrow + d]);
  float t2 = bf2f(kvraw[rrow + d + 64]);
  float c = cosT[(s << 6) + d], sn = sinT[(s << 6) + d];
  size_t orow = ((size_t)(b * NS + s)) * NHD;
  kout[orow + d]      = f2bf(t1 * c - t2 * sn);
  kout[orow + d + 64] = f2bf(t2 * c + t1 * sn);
  // V transposed: VT[b][d][s]
  vtout[((size_t)(b * 128 + d)) * NS + s]      = kvraw[rrow + 128 + d];
  vtout[((size_t)(b * 128 + d + 64)) * NS + s] = kvraw[rrow + 128 + d + 64];
}

// ---------------- GEMM: C[M,N] = A[M,K](bf16) @ W[N,K]^T(bf16) ----------------
// 128x128 tile, BK=64, 4 waves (2x2), 4x4 acc of 16x16x32 MFMA per wave.
// EPI: 0 = store bf16; 1 = store fp32 acc + fp32 Aux; 2 = store bf16 silu(Aux_bf16)*acc
template <int EPI>
__global__ __launch_bounds__(256) void gemm_kernel(const u16* __restrict__ A,
                                                   const u16* __restrict__ W,
                                                   void* Out,
                                                   const void* Aux,
                                                   int M, int N, int K) {
  __shared__ __align__(16) u16 Asm[128 * 64];
  __shared__ __align__(16) u16 Bsm[128 * 64];
  const int tid = threadIdx.x, wave = tid >> 6, lane = tid & 63;
  const int m0 = blockIdx.y * 128, n0 = blockIdx.x * 128;
  const int wr = wave >> 1, wc = wave & 1;

  f32x4 acc[4][4];
#pragma unroll
  for (int i = 0; i < 4; ++i)
#pragma unroll
    for (int j = 0; j < 4; ++j) acc[i][j] = (f32x4){0.f, 0.f, 0.f, 0.f};

  for (int k0 = 0; k0 < K; k0 += 64) {
#pragma unroll
    for (int p = 0; p < 4; ++p) {
      int linear = p * 4096 + tid * 16;        // byte offset within 16KB tile
      int r = linear >> 7;                     // 128B per row (64 bf16)
      int kk = (linear & 127) >> 1;
      int ldsoff = p * 4096 + wave * 1024;     // wave-uniform dest base
      async_cp16(A + (size_t)(m0 + r) * K + k0 + kk, (char*)Asm + ldsoff);
      async_cp16(W + (size_t)(n0 + r) * K + k0 + kk, (char*)Bsm + ldsoff);
    }
    __syncthreads();
#pragma unroll
    for (int kk = 0; kk < 64; kk += 32) {
      const int ko = kk + (lane >> 4) * 8;
      bf16x8 af[4], bfr[4];
#pragma unroll
      for (int mi = 0; mi < 4; ++mi)
        af[mi] = *(const bf16x8*)&Asm[(wr * 64 + mi * 16 + (lane & 15)) * 64 + ko];
#pragma unroll
      for (int ni = 0; ni < 4; ++ni)
        bfr[ni] = *(const bf16x8*)&Bsm[(wc * 64 + ni * 16 + (lane & 15)) * 64 + ko];
#pragma unroll
      for (int mi = 0; mi < 4; ++mi)
#pragma unroll
        for (int ni = 0; ni < 4; ++ni)
          acc[mi][ni] = __builtin_amdgcn_mfma_f32_16x16x32_bf16(af[mi], bfr[ni], acc[mi][ni], 0, 0, 0);
    }
    __syncthreads();
  }

#pragma unroll
  for (int mi = 0; mi < 4; ++mi) {
    const int row_b = m0 + wr * 64 + mi * 16 + (lane >> 4) * 4;
#pragma unroll
    for (int ni = 0; ni < 4; ++ni) {
      const int col = n0 + wc * 64 + ni * 16 + (lane & 15);
#pragma unroll
      for (int r = 0; r < 4; ++r) {
        size_t idx = (size_t)(row_b + r) * N + col;
        float v = acc[mi][ni][r];
        if constexpr (EPI == 0) {
          ((u16*)Out)[idx] = f2bf(v);
        } else if constexpr (EPI == 1) {
          ((float*)Out)[idx] = v + ((const float*)Aux)[idx];
        } else {
          float a1 = bf2f(((const u16*)Aux)[idx]);
          float s = a1 / (1.0f + expf(-a1));   // silu
          ((u16*)Out)[idx] = f2bf(s * v);
        }
      }
    }
  }
}

// ---------------- Flash attention with ALiBi + causal ----------------
// grid (S/64, B*H), 256 threads = 4 waves; wave = 16 q rows; KV tiles of 64.
// K [kv][128] and VT [d][64] staged in LDS via global_load_lds with XOR-swizzled
// SOURCE (linear dest), so all QK/PV fragments are conflict-free ds_read_b128.
__global__ __launch_bounds__(256) void attn_kernel(const u16* __restrict__ q,
                                                   const u16* __restrict__ kg,
                                                   const u16* __restrict__ vt,
                                                   u16* __restrict__ out) {
  __shared__ __align__(16) u16 Klds[64 * 128];   // [kv][k-slot swizzled] 16KB
  __shared__ __align__(16) u16 Vlds[128 * 64];   // [d][kv-slot swizzled] 16KB
  __shared__ __align__(16) u16 Plds[4][16 * 72]; // per-wave P, padded rows
  const int tid = threadIdx.x, wave = tid >> 6, lane = tid & 63;
  const int qt = (gridDim.x - 1) - blockIdx.x;   // heavy blocks first
  const int q0 = qt * 64;
  const int bh = blockIdx.y, b = bh >> 4, h = bh & 15;
  const float slope = exp2f(-0.5f * (float)(h + 1));
  const int lm = lane & 15, lg = lane >> 4;
  const int crow = lg * 4;

  // Q A-fragments (q pre-scaled by 1/sqrt(HD))
  bf16x8 qf[4];
  {
    const int qrow = q0 + wave * 16 + lm;
    const u16* qbase = q + ((size_t)bh * NS + qrow) * NHD + lg * 8;
#pragma unroll
    for (int kc = 0; kc < 4; ++kc) qf[kc] = *(const bf16x8*)(qbase + kc * 32);
  }

  float Mr[4], Lr[4];
  f32x4 O[8];
#pragma unroll
  for (int r = 0; r < 4; ++r) { Mr[r] = -__builtin_inff(); Lr[r] = 0.f; }
#pragma unroll
  for (int t = 0; t < 8; ++t) O[t] = (f32x4){0.f, 0.f, 0.f, 0.f};

  const int kslotK = tid & 15;            // K staging: 16B slot within 256B row
  const int kvK    = tid >> 4;            // K staging: row (plus p*16)
  const int sV     = tid & 7;             // V staging: 16B slot within 128B row
  const int dV     = tid >> 3;            // V staging: row (plus p*32)
  u16* pw = Plds[wave];

  const int ntiles = qt + 1;
  for (int t0 = 0; t0 < ntiles; ++t0) {
    const int kv0 = t0 * 64;
    __syncthreads();   // prior-iter LDS reads done before overwrite
    // stage K tile: LDS slot s holds global k-group (s ^ (kv&7))
#pragma unroll
    for (int p = 0; p < 4; ++p) {
      int kv = p * 16 + kvK;
      const u16* src = kg + ((size_t)b * NS + kv0 + kv) * NHD + ((kslotK ^ (kv & 7)) * 8);
      async_cp16(src, (char*)Klds + p * 4096 + wave * 1024);
    }
    // stage VT tile: LDS slot s holds global kv-group (s ^ (d&7))
#pragma unroll
    for (int p = 0; p < 4; ++p) {
      int d = p * 32 + dV;
      const u16* src = vt + ((size_t)b * 128 + d) * NS + kv0 + ((sV ^ (d & 7)) * 8);
      async_cp16(src, (char*)Vlds + p * 4096 + wave * 1024);
    }
    __syncthreads();   // staged data visible

    // ---- QK^T: 4 sub-tiles of 16 kv ----
    f32x4 sc[4];
#pragma unroll
    for (int sub = 0; sub < 4; ++sub) sc[sub] = (f32x4){0.f, 0.f, 0.f, 0.f};
#pragma unroll
    for (int sub = 0; sub < 4; ++sub) {
      const int kv = sub * 16 + lm;
#pragma unroll
      for (int kc = 0; kc < 4; ++kc) {
        const int slot = (kc * 4 + lg) ^ (kv & 7);
        bf16x8 kf = *(const bf16x8*)((const char*)Klds + kv * 256 + slot * 16);
        sc[sub] = __builtin_amdgcn_mfma_f32_16x16x32_bf16(qf[kc], kf, sc[sub], 0, 0, 0);
      }
    }

    // ---- ALiBi + causal + online softmax ----
    float esc[4], pp[4][4];
#pragma unroll
    for (int r = 0; r < 4; ++r) {
      const int sq = q0 + wave * 16 + crow + r;
      float v[4];
#pragma unroll
      for (int sub = 0; sub < 4; ++sub) {
        const int kc_ = kv0 + sub * 16 + lm;
        v[sub] = (kc_ <= sq) ? sc[sub][r] - slope * (float)(sq - kc_) : -1e9f;
      }
      float mx = fmaxf(fmaxf(v[0], v[1]), fmaxf(v[2], v[3]));
      mx = fmaxf(mx, __shfl_xor(mx, 1));
      mx = fmaxf(mx, __shfl_xor(mx, 2));
      mx = fmaxf(mx, __shfl_xor(mx, 4));
      mx = fmaxf(mx, __shfl_xor(mx, 8));
      const float newM = fmaxf(Mr[r], mx);
      esc[r] = __expf(Mr[r] - newM);
      float rs = 0.f;
#pragma unroll
      for (int sub = 0; sub < 4; ++sub) { pp[sub][r] = __expf(v[sub] - newM); rs += pp[sub][r]; }
      rs += __shfl_xor(rs, 1);
      rs += __shfl_xor(rs, 2);
      rs += __shfl_xor(rs, 4);
      rs += __shfl_xor(rs, 8);
      Lr[r] = Lr[r] * esc[r] + rs;
      Mr[r] = newM;
    }
#pragma unroll
    for (int t = 0; t < 8; ++t) {
      O[t][0] *= esc[0]; O[t][1] *= esc[1]; O[t][2] *= esc[2]; O[t][3] *= esc[3];
    }

    // ---- P -> wave-private LDS (padded rows, 144B) ----
#pragma unroll
    for (int sub = 0; sub < 4; ++sub)
#pragma unroll
      for (int r = 0; r < 4; ++r)
        pw[(crow + r) * 72 + sub * 16 + lm] = f2bf(pp[sub][r]);

    // ---- PV: O[16q x 128d] += P[16x64] @ V[64x128] ----
    bf16x8 pa0 = *(const bf16x8*)&pw[lm * 72 + lg * 8];
    bf16x8 pa1 = *(const bf16x8*)&pw[lm * 72 + 32 + lg * 8];
#pragma unroll
    for (int dt = 0; dt < 8; ++dt) {
      const int d = dt * 16 + lm;
      const int s0 = (lg) ^ (d & 7);
      const int s1 = (4 + lg) ^ (d & 7);
      bf16x8 vf0 = *(const bf16x8*)((const char*)Vlds + d * 128 + s0 * 16);
      bf16x8 vf1 = *(const bf16x8*)((const char*)Vlds + d * 128 + s1 * 16);
      O[dt] = __builtin_amdgcn_mfma_f32_16x16x32_bf16(pa0, vf0, O[dt], 0, 0, 0);
      O[dt] = __builtin_amdgcn_mfma_f32_16x16x32_bf16(pa1, vf1, O[dt], 0, 0, 0);
    }
  }

  // ---- normalize + store [B,S,H*HD] ----
#pragma unroll
  for (int dt = 0; dt < 8; ++dt) {
#pragma unroll
    for (int r = 0; r < 4; ++r) {
      const int sq = q0 + wave * 16 + crow + r;
      out[((size_t)b * NS + sq) * ND + h * NHD + dt * 16 + lm] = f2bf(O[dt][r] / Lr[r]);
    }
  }
}

// ---------------- host ----------------
extern "C" void kernel_launch(void* const* d_in, const int* in_sizes, int n_in,
                              void* d_out, int out_size, void* d_ws, size_t ws_size,
                              hipStream_t stream) {
  const float* x   = (const float*)d_in[0];
  const float* wn1 = (const float*)d_in[2];
  const float* wn2 = (const float*)d_in[3];
  const float* qw  = (const float*)d_in[4];
  const float* kvw = (const float*)d_in[5];
  const float* ow  = (const float*)d_in[6];
  const float* w1  = (const float*)d_in[7];
  const float* w2  = (const float*)d_in[8];
  const float* w3  = (const float*)d_in[9];
  float* out = (float*)d_out;

  const size_t MiB = 1024 * 1024;
  const size_t NEED = 161 * MiB;
  if (ws_size < NEED) return;

  char* ws = (char*)d_ws;
  u16*   R_W   = (u16*)(ws);
  u16*   Hbf   = (u16*)(ws + 32 * MiB);
  float* COS   = (float*)(ws + 48 * MiB);
  float* SIN   = (float*)(ws + 48 * MiB + 512 * 1024);
  u16*   QRAW  = (u16*)(ws + 49 * MiB);
  u16*   AO    = QRAW;                       // alias: QRAW dead after rope_q
  u16*   QB    = (u16*)(ws + 65 * MiB);
  u16*   KB    = (u16*)(ws + 81 * MiB);
  u16*   VT    = (u16*)(ws + 82 * MiB);      // V transposed [B][128][S]
  u16*   KVRAW = (u16*)(ws + 83 * MiB);
  float* X2    = (float*)(ws + 65 * MiB);    // alias: QB/KB/VT/KVRAW dead after attn
  u16*   A1    = (u16*)(ws + 97 * MiB);

  auto cvt = [&](const float* src, u16* dst, size_t n) {
    int n4 = (int)(n / 4);
    cvt_bf16_kernel<<<(n4 + 255) / 256, 256, 0, stream>>>(src, dst, n4);
  };

  rope_table_kernel<<<(NS * 64 + 255) / 256, 256, 0, stream>>>(COS, SIN);

  rmsnorm_kernel<<<NBS, 256, 0, stream>>>(x, wn1, Hbf);

  cvt(qw, R_W, (size_t)ND * ND);
  gemm_kernel<0><<<dim3(ND / 128, NBS / 128), 256, 0, stream>>>(Hbf, R_W, (void*)QRAW, nullptr, NBS, ND, ND);
  cvt(kvw, R_W, (size_t)256 * ND);
  gemm_kernel<0><<<dim3(256 / 128, NBS / 128), 256, 0, stream>>>(Hbf, R_W, (void*)KVRAW, nullptr, NBS, 256, ND);

  rope_q_kernel<<<(NB * NS * NH * 64) / 256, 256, 0, stream>>>(QRAW, COS, SIN, QB);
  rope_kv_kernel<<<(NB * NS * 64) / 256, 256, 0, stream>>>(KVRAW, COS, SIN, KB, VT);

  attn_kernel<<<dim3(NS / 64, NB * NH), 256, 0, stream>>>(QB, KB, VT, AO);

  cvt(ow, R_W, (size_t)ND * ND);
  gemm_kernel<1><<<dim3(ND / 128, NBS / 128), 256, 0, stream>>>(AO, R_W, (void*)X2, (const void*)x, NBS, ND, ND);

  rmsnorm_kernel<<<NBS, 256, 0, stream>>>(X2, wn2, Hbf);

  cvt(w1, R_W, (size_t)NFF * ND);
  gemm_kernel<0><<<dim3(NFF / 128, NBS / 128), 256, 0, stream>>>(Hbf, R_W, (void*)A1, nullptr, NBS, NFF, ND);
  cvt(w2, R_W, (size_t)NFF * ND);
  gemm_kernel<2><<<dim3(NFF / 128, NBS / 128), 256, 0, stream>>>(Hbf, R_W, (void*)A1, (const void*)A1, NBS, NFF, ND);

  cvt(w3, R_W, (size_t)ND * NFF);
  gemm_kernel<1><<<dim3(ND / 128, NBS / 128), 256, 0, stream>>>(A1, R_W, (void*)out, (const void*)X2, NBS, ND, NFF);
}